// Round 10
// baseline (239.177 us; speedup 1.0000x reference)
//
#include <hip/hip_runtime.h>

#define BATCH 65536
#define TB 16

typedef _Float16 half8 __attribute__((ext_vector_type(8)));
typedef float fx4 __attribute__((ext_vector_type(4)));

// workspace layout (halves)
#define PW1B_OFF 0        // [4][256][32]  W1 base rows (k<110, pad->128)
#define PW1F_OFF 32768    // [256][32]     W1 feat rows, k-map [feat_i(15) 0 feat_j(15) 0]
#define PW2_OFF  40960    // [8][256][32]
#define PWR_OFF  106496   // [8][256][32]
#define PWH_OFF  172032   // [8][16][32]   [mean_w | lstd_w | pad]
#define WS_TOTAL 176128

// A-layout index for a 16-row x 256-col tile, fragment-major:
// a-frag read for (kt,q,l16) at ((kt*4+q)*16+l16)*8 -> lane-contiguous b128.
#define HIDX(row, col) (((((col) >> 5) * 4 + (((col) >> 3) & 3)) * 16 + (row)) * 8 + ((col) & 7))

__global__ __launch_bounds__(256) void prep_weights(
    const float* __restrict__ w1, const float* __restrict__ w2,
    const float* __restrict__ wr, const float* __restrict__ wm,
    const float* __restrict__ wl, _Float16* __restrict__ ws)
{
  int idx = blockIdx.x * 256 + threadIdx.x;
  if (idx < 32768) {            // pw1b
    int kk = idx & 31, n = (idx >> 5) & 255, kt = idx >> 13;
    int k = kt * 32 + kk;
    ws[idx] = (k < 110) ? (_Float16)w1[k * 256 + n] : (_Float16)0.f;
  } else if (idx < 40960) {     // pw1f: kk 0-14 feat_i rows 113+, kk 16-30 feat_j rows 131+
    int t = idx - 32768;
    int kk = t & 31, n = t >> 5;
    _Float16 v = (_Float16)0.f;
    if (kk < 15)                  v = (_Float16)w1[(113 + kk) * 256 + n];
    else if (kk >= 16 && kk < 31) v = (_Float16)w1[(131 + (kk - 16)) * 256 + n];
    ws[idx] = v;
  } else if (idx < 106496) {    // pw2
    int t = idx - 40960;
    int kk = t & 31, n = (t >> 5) & 255, kt = t >> 13;
    ws[idx] = (_Float16)w2[(kt * 32 + kk) * 256 + n];
  } else if (idx < 172032) {    // pwr
    int t = idx - 106496;
    int kk = t & 31, n = (t >> 5) & 255, kt = t >> 13;
    ws[idx] = (_Float16)wr[(kt * 32 + kk) * 256 + n];
  } else if (idx < WS_TOTAL) {  // pwh
    int t = idx - 172032;
    int kk = t & 31, n = (t >> 5) & 15, kt = t >> 9;
    int k = kt * 32 + kk;
    _Float16 v = (_Float16)0.f;
    if (n < 4) v = (_Float16)wm[k * 4 + n];
    else if (n < 8) v = (_Float16)wl[k * 4 + (n - 4)];
    ws[PWH_OFF + t] = v;
  }
}

// R9 post-mortem: 52.5 KB LDS still only fits 2 blocks/CU (3x53.76KB grazes
// the 160KB edge + driver reserve). R10: process perms in 2 chunks of 3 ->
// H1 24KB, total LDS ~28.5KB -> 4 blocks/CU (wave-cap 32 = 100% occupancy),
// doubling resident waves for latency hiding. agg accumulates across chunks
// in registers; +2 barriers but phases stay 24-48 MFMAs long (not R7's
// 8-MFMA micro-phases). Math identical to R8/R9 (verified absmax 0.031).
__global__ __launch_bounds__(512) void actor_fused(
    const float* __restrict__ obs, const float* __restrict__ lemb,
    const float* __restrict__ w1, const _Float16* __restrict__ ws,
    const float* __restrict__ b1, const float* __restrict__ b2,
    const float* __restrict__ br, const float* __restrict__ bm,
    const float* __restrict__ bl, float* __restrict__ out)
{
  __shared__ __align__(16) _Float16 H1[3 * 16 * 256]; // 24 KB: base / h1 chunk / agg / r
  __shared__ __align__(16) _Float16 Os[3 * 16 * 16];  // 1.5 KB: compact obj tiles
  __shared__ __align__(16) _Float16 Bs[6 * 256];      // 3 KB: fused per-perm biases

  const _Float16* __restrict__ pw1b = ws + PW1B_OFF;
  const _Float16* __restrict__ pw1f = ws + PW1F_OFF;
  const _Float16* __restrict__ pw2  = ws + PW2_OFF;
  const _Float16* __restrict__ pwr  = ws + PWR_OFF;
  const _Float16* __restrict__ pwh  = ws + PWH_OFF;

  const int tid  = threadIdx.x;
  const int wave = tid >> 6;        // 0..7
  const int lane = tid & 63;
  const int q    = lane >> 4;
  const int l16  = lane & 15;
  const int colbase = wave * 32;    // this wave's 32 output cols
  const int rowbase = blockIdx.x * TB;

  // ---- stage base (16 rows x K=128) into H1 tile 0 ----
  for (int idx = tid; idx < 2048; idx += 512) {
    int r = idx >> 7, c = idx & 127;
    float v = 0.f;
    if (c < 100)      v = lemb[(rowbase + r) * 100 + c];
    else if (c < 110) v = obs[(rowbase + r) * 55 + (c - 100)];
    H1[HIDX(r, c)] = (_Float16)v;
  }
  // ---- compact obj tiles: 3 objects x 16 rows x 16 k (15 feats + pad) ----
  for (int idx = tid; idx < 768; idx += 512) {
    int o = idx >> 8, rem = idx & 255, r = rem >> 4, c = rem & 15;
    float v = (c < 15) ? obs[(rowbase + r) * 55 + 10 + o * 15 + c] : 0.f;
    Os[o * 256 + ((c >> 3) * 16 + r) * 8 + (c & 7)] = (_Float16)v;
  }
  // ---- fused per-perm biases: b1 + W1[onehot_i row] + W1[onehot_j row] ----
  for (int idx = tid; idx < 1536; idx += 512) {
    int p = idx >> 8, c = idx & 255;
    int oi = p >> 1, oj = (1161 >> (2 * p)) & 3;
    Bs[idx] = (_Float16)(b1[c] + w1[(110 + oi) * 256 + c] + w1[(128 + oj) * 256 + c]);
  }
  __syncthreads();

  const fx4 zero4 = {0.f, 0.f, 0.f, 0.f};

  // ---- U = base @ W1base (K=128), M=16, this wave's 32 cols ----
  fx4 u[2];
  u[0] = zero4; u[1] = zero4;
  #pragma unroll 2
  for (int kt = 0; kt < 4; ++kt) {
    half8 a = *(const half8*)&H1[((kt * 4 + q) * 16 + l16) * 8];
    #pragma unroll
    for (int nt = 0; nt < 2; ++nt) {
      half8 b = *(const half8*)&pw1b[(kt * 256 + colbase + nt * 16 + l16) * 32 + q * 8];
      u[nt] = __builtin_amdgcn_mfma_f32_16x16x32_f16(a, b, u[nt], 0, 0, 0);
    }
  }
  __syncthreads();  // base region of H1 dead; GEMM1 may overwrite

  fx4 agg[2];
  agg[0] = zero4; agg[1] = zero4;

  // ---- 2 chunks of 3 perms ----
  #pragma unroll
  for (int ch = 0; ch < 2; ++ch) {
    // GEMM1-chunk: h1_p = relu(U + F_p @ W1f + bias_p), p = 3ch..3ch+2, K=32
    // A k-map: quad 0,1 -> feat_i (k 0..15), quad 2,3 -> feat_j (k 16..31)
    #pragma unroll
    for (int pp = 0; pp < 3; ++pp) {
      const int p = ch * 3 + pp;
      const int oi = p >> 1;
      const int oj = (1161 >> (2 * p)) & 3;
      const int o = (q < 2) ? oi : oj;
      half8 af = *(const half8*)&Os[o * 256 + ((q & 1) * 16 + l16) * 8];
      #pragma unroll
      for (int nt = 0; nt < 2; ++nt) {
        int col = colbase + nt * 16 + l16;
        half8 b = *(const half8*)&pw1f[col * 32 + q * 8];
        fx4 acc1 = u[nt];
        acc1 = __builtin_amdgcn_mfma_f32_16x16x32_f16(af, b, acc1, 0, 0, 0);
        float bs = (float)Bs[p * 256 + col];
        #pragma unroll
        for (int rr = 0; rr < 4; ++rr) {
          float h = acc1[rr] + bs;
          H1[pp * 4096 + HIDX(q * 4 + rr, col)] = (_Float16)(h > 0.f ? h : 0.f);
        }
      }
    }
    __syncthreads();

    // GEMM2-chunk: M=48 (3 perms x 16 rows), K=256
    fx4 acc[6];
    #pragma unroll
    for (int i = 0; i < 6; ++i) acc[i] = zero4;
    #pragma unroll 2
    for (int kt = 0; kt < 8; ++kt) {
      half8 a[3];
      #pragma unroll
      for (int pp = 0; pp < 3; ++pp)
        a[pp] = *(const half8*)&H1[pp * 4096 + ((kt * 4 + q) * 16 + l16) * 8];
      #pragma unroll
      for (int nt = 0; nt < 2; ++nt) {
        half8 b = *(const half8*)&pw2[(kt * 256 + colbase + nt * 16 + l16) * 32 + q * 8];
        #pragma unroll
        for (int pp = 0; pp < 3; ++pp)
          acc[pp * 2 + nt] = __builtin_amdgcn_mfma_f32_16x16x32_f16(a[pp], b, acc[pp * 2 + nt], 0, 0, 0);
      }
    }
    // relu + accumulate into agg
    #pragma unroll
    for (int nt = 0; nt < 2; ++nt) {
      float bs = b2[colbase + nt * 16 + l16];
      #pragma unroll
      for (int pp = 0; pp < 3; ++pp)
        #pragma unroll
        for (int rr = 0; rr < 4; ++rr) {
          float h = acc[pp * 2 + nt][rr] + bs;
          if (h > 0.f) agg[nt][rr] += h;
        }
    }
    __syncthreads();  // all waves done reading H1 before next chunk / agg stage
  }

  // stage agg -> H1 tile 0
  #pragma unroll
  for (int nt = 0; nt < 2; ++nt) {
    int col = colbase + nt * 16 + l16;
    #pragma unroll
    for (int rr = 0; rr < 4; ++rr)
      H1[HIDX(q * 4 + rr, col)] = (_Float16)agg[nt][rr];
  }
  __syncthreads();

  // ---- GEMM3: r = relu(agg @ rho + br), M=16, K=256; r -> H1 tile 1 ----
  fx4 acc3[2];
  acc3[0] = zero4; acc3[1] = zero4;
  #pragma unroll 2
  for (int kt = 0; kt < 8; ++kt) {
    half8 a = *(const half8*)&H1[((kt * 4 + q) * 16 + l16) * 8];
    #pragma unroll
    for (int nt = 0; nt < 2; ++nt) {
      half8 b = *(const half8*)&pwr[(kt * 256 + colbase + nt * 16 + l16) * 32 + q * 8];
      acc3[nt] = __builtin_amdgcn_mfma_f32_16x16x32_f16(a, b, acc3[nt], 0, 0, 0);
    }
  }
  #pragma unroll
  for (int nt = 0; nt < 2; ++nt) {
    int col = colbase + nt * 16 + l16;
    float bs = br[col];
    #pragma unroll
    for (int rr = 0; rr < 4; ++rr) {
      float h = acc3[nt][rr] + bs;
      H1[4096 + HIDX(q * 4 + rr, col)] = (_Float16)(h > 0.f ? h : 0.f);
    }
  }
  __syncthreads();

  // ---- heads: wave 0 computes [mean | log_std] = r @ PWh (N padded 16) ----
  if (wave == 0) {
    fx4 a4 = zero4;
    for (int kt = 0; kt < 8; ++kt) {
      half8 a = *(const half8*)&H1[4096 + ((kt * 4 + q) * 16 + l16) * 8];
      half8 b = *(const half8*)&pwh[(kt * 16 + l16) * 32 + q * 8];
      a4 = __builtin_amdgcn_mfma_f32_16x16x32_f16(a, b, a4, 0, 0, 0);
    }
    int gr = rowbase + q * 4;
    if (l16 < 4) {
      float bias = bm[l16];
      #pragma unroll
      for (int rr = 0; rr < 4; ++rr) out[(gr + rr) * 4 + l16] = a4[rr] + bias;
    } else if (l16 < 8) {
      int c = l16 - 4;
      float bias = bl[c];
      #pragma unroll
      for (int rr = 0; rr < 4; ++rr) {
        float v = a4[rr] + bias;
        v = v < -20.f ? -20.f : (v > 2.f ? 2.f : v);
        out[BATCH * 4 + (gr + rr) * 4 + c] = v;
      }
    }
  }
}

extern "C" void kernel_launch(void* const* d_in, const int* in_sizes, int n_in,
                              void* d_out, int out_size, void* d_ws, size_t ws_size,
                              hipStream_t stream) {
  const float* obs  = (const float*)d_in[0];
  const float* lemb = (const float*)d_in[1];
  const float* w1   = (const float*)d_in[2];
  const float* b1   = (const float*)d_in[3];
  const float* w2   = (const float*)d_in[4];
  const float* b2   = (const float*)d_in[5];
  const float* wr   = (const float*)d_in[6];
  const float* br   = (const float*)d_in[7];
  const float* wm   = (const float*)d_in[8];
  const float* bm   = (const float*)d_in[9];
  const float* wl   = (const float*)d_in[10];
  const float* bl   = (const float*)d_in[11];
  float* out = (float*)d_out;
  _Float16* ws = (_Float16*)d_ws;

  hipLaunchKernelGGL(prep_weights, dim3(WS_TOTAL / 256), dim3(256), 0, stream,
                     w1, w2, wr, wm, wl, ws);
  hipLaunchKernelGGL(actor_fused, dim3(BATCH / TB), dim3(512), 0, stream,
                     obs, lemb, w1, (const _Float16*)ws, b1, b2, br, bm, bl, out);
}

// Round 11
// 228.818 us; speedup vs baseline: 1.0453x; 1.0453x over previous
//
#include <hip/hip_runtime.h>

#define BATCH 65536
#define TB 32

typedef _Float16 half8 __attribute__((ext_vector_type(8)));
typedef float fx4 __attribute__((ext_vector_type(4)));

// workspace layout (halves)
#define PW1B_OFF 0        // [4][256][32]  W1 base rows (k<110, pad->128)
#define PW1F_OFF 32768    // [256][32]     W1 feat rows, k-map [feat_i(15) 0 feat_j(15) 0]
#define PW2_OFF  40960    // [8][256][32]
#define PWR_OFF  106496   // [8][256][32]
#define PWH_OFF  172032   // [8][16][32]   [mean_w | lstd_w | pad]
#define WS_TOTAL 176128

// A-layout index inside a 16-row x (<=256)-col fragment-major tile:
// a-frag read for (kt,q,l16) at ((kt*4+q)*16+l16)*8 -> lane-contiguous b128.
#define HIDX(row, col) (((((col) >> 5) * 4 + (((col) >> 3) & 3)) * 16 + (row)) * 8 + ((col) & 7))

__global__ __launch_bounds__(256) void prep_weights(
    const float* __restrict__ w1, const float* __restrict__ w2,
    const float* __restrict__ wr, const float* __restrict__ wm,
    const float* __restrict__ wl, _Float16* __restrict__ ws)
{
  int idx = blockIdx.x * 256 + threadIdx.x;
  if (idx < 32768) {            // pw1b
    int kk = idx & 31, n = (idx >> 5) & 255, kt = idx >> 13;
    int k = kt * 32 + kk;
    ws[idx] = (k < 110) ? (_Float16)w1[k * 256 + n] : (_Float16)0.f;
  } else if (idx < 40960) {     // pw1f: kk 0-14 feat_i rows 113+, kk 16-30 feat_j rows 131+
    int t = idx - 32768;
    int kk = t & 31, n = t >> 5;
    _Float16 v = (_Float16)0.f;
    if (kk < 15)                  v = (_Float16)w1[(113 + kk) * 256 + n];
    else if (kk >= 16 && kk < 31) v = (_Float16)w1[(131 + (kk - 16)) * 256 + n];
    ws[idx] = v;
  } else if (idx < 106496) {    // pw2
    int t = idx - 40960;
    int kk = t & 31, n = (t >> 5) & 255, kt = t >> 13;
    ws[idx] = (_Float16)w2[(kt * 32 + kk) * 256 + n];
  } else if (idx < 172032) {    // pwr
    int t = idx - 106496;
    int kk = t & 31, n = (t >> 5) & 255, kt = t >> 13;
    ws[idx] = (_Float16)wr[(kt * 32 + kk) * 256 + n];
  } else if (idx < WS_TOTAL) {  // pwh
    int t = idx - 172032;
    int kk = t & 31, n = (t >> 5) & 15, kt = t >> 9;
    int k = kt * 32 + kk;
    _Float16 v = (_Float16)0.f;
    if (n < 4) v = (_Float16)wm[k * 4 + n];
    else if (n < 8) v = (_Float16)wl[k * 4 + (n - 4)];
    ws[PWH_OFF + t] = v;
  }
}

// R10 post-mortem: occupancy pinned at ~2x512-thr blocks/CU regardless of LDS
// (41-43% across 62/52/29 KB); chunking to 3 perms halved b-load amortization
// -> +0.5 GB L2 -> regression. R11: TB=32 (m=2 row-tiles/wave) restores
// 6-tile b-amortization in GEMM2 within 3-perm chunks, halves U/G3/heads
// b-traffic per row, and cuts barrier drains 12->7 per 32 rows (base in its
// own LDS buffer so U needs no trailing barrier). Math identical to R8-R10.
__global__ __launch_bounds__(512) void actor_fused(
    const float* __restrict__ obs, const float* __restrict__ lemb,
    const float* __restrict__ w1, const _Float16* __restrict__ ws,
    const float* __restrict__ b1, const float* __restrict__ b2,
    const float* __restrict__ br, const float* __restrict__ bm,
    const float* __restrict__ bl, float* __restrict__ out)
{
  __shared__ __align__(16) _Float16 H1[6 * 16 * 256]; // 48 KB: h1 chunk (3p x 2m) / agg / r
  __shared__ __align__(16) _Float16 Bb[2 * 16 * 128]; //  8 KB: base, 2 row-tiles x K=128
  __shared__ __align__(16) _Float16 Os[3 * 2 * 256];  //  3 KB: obj tiles, 3 obj x 2 row-tiles
  __shared__ __align__(16) _Float16 Bs[6 * 256];      //  3 KB: fused per-perm biases

  const _Float16* __restrict__ pw1b = ws + PW1B_OFF;
  const _Float16* __restrict__ pw1f = ws + PW1F_OFF;
  const _Float16* __restrict__ pw2  = ws + PW2_OFF;
  const _Float16* __restrict__ pwr  = ws + PWR_OFF;
  const _Float16* __restrict__ pwh  = ws + PWH_OFF;

  const int tid  = threadIdx.x;
  const int wave = tid >> 6;        // 0..7
  const int lane = tid & 63;
  const int q    = lane >> 4;
  const int l16  = lane & 15;
  const int colbase = wave * 32;    // this wave's 32 output cols
  const int rowbase = blockIdx.x * TB;

  // ---- stage base (32 rows x K=128) into Bb ----
  for (int idx = tid; idx < 4096; idx += 512) {
    int r = idx >> 7, c = idx & 127;
    float v = 0.f;
    if (c < 100)      v = lemb[(rowbase + r) * 100 + c];
    else if (c < 110) v = obs[(rowbase + r) * 55 + (c - 100)];
    Bb[(r >> 4) * 2048 + HIDX(r & 15, c)] = (_Float16)v;
  }
  // ---- obj tiles: 3 objects x 32 rows x 16 k (15 feats + pad) ----
  for (int idx = tid; idx < 1536; idx += 512) {
    int o = idx >> 9, rem = idx & 511, r = rem >> 4, c = rem & 15;
    float v = (c < 15) ? obs[(rowbase + r) * 55 + 10 + o * 15 + c] : 0.f;
    Os[o * 512 + (r >> 4) * 256 + ((c >> 3) * 16 + (r & 15)) * 8 + (c & 7)] = (_Float16)v;
  }
  // ---- fused per-perm biases: b1 + W1[onehot_i row] + W1[onehot_j row] ----
  for (int idx = tid; idx < 1536; idx += 512) {
    int p = idx >> 8, c = idx & 255;
    int oi = p >> 1, oj = (1161 >> (2 * p)) & 3;
    Bs[idx] = (_Float16)(b1[c] + w1[(110 + oi) * 256 + c] + w1[(128 + oj) * 256 + c]);
  }
  __syncthreads();

  const fx4 zero4 = {0.f, 0.f, 0.f, 0.f};

  // ---- U = base @ W1base (K=128), M=32 (2 row-tiles), this wave's 32 cols ----
  fx4 u[4];  // [m][nt]
  #pragma unroll
  for (int i = 0; i < 4; ++i) u[i] = zero4;
  #pragma unroll 2
  for (int kt = 0; kt < 4; ++kt) {
    half8 a[2];
    #pragma unroll
    for (int m = 0; m < 2; ++m)
      a[m] = *(const half8*)&Bb[m * 2048 + ((kt * 4 + q) * 16 + l16) * 8];
    #pragma unroll
    for (int nt = 0; nt < 2; ++nt) {
      half8 b = *(const half8*)&pw1b[(kt * 256 + colbase + nt * 16 + l16) * 32 + q * 8];
      #pragma unroll
      for (int m = 0; m < 2; ++m)
        u[m * 2 + nt] = __builtin_amdgcn_mfma_f32_16x16x32_f16(a[m], b, u[m * 2 + nt], 0, 0, 0);
    }
  }
  // no barrier: Bb is never overwritten; H1 not yet read by anyone

  // preload the (perm-invariant) GEMM1 feature-weight fragments
  half8 b1f[2];
  #pragma unroll
  for (int nt = 0; nt < 2; ++nt)
    b1f[nt] = *(const half8*)&pw1f[(colbase + nt * 16 + l16) * 32 + q * 8];

  fx4 agg[4];  // [m][nt]
  #pragma unroll
  for (int i = 0; i < 4; ++i) agg[i] = zero4;

  // ---- 2 chunks of 3 perms ----
  #pragma unroll
  for (int ch = 0; ch < 2; ++ch) {
    // GEMM1-chunk: h1_p = relu(U + F_p @ W1f + bias_p), K=32
    // A k-map: quad 0,1 -> feat_i (k 0..15), quad 2,3 -> feat_j (k 16..31)
    #pragma unroll
    for (int pp = 0; pp < 3; ++pp) {
      const int p = ch * 3 + pp;
      const int oi = p >> 1;
      const int oj = (1161 >> (2 * p)) & 3;
      const int o = (q < 2) ? oi : oj;
      half8 af[2];
      #pragma unroll
      for (int m = 0; m < 2; ++m)
        af[m] = *(const half8*)&Os[o * 512 + m * 256 + ((q & 1) * 16 + l16) * 8];
      #pragma unroll
      for (int nt = 0; nt < 2; ++nt) {
        int col = colbase + nt * 16 + l16;
        float bs = (float)Bs[p * 256 + col];
        #pragma unroll
        for (int m = 0; m < 2; ++m) {
          fx4 acc1 = u[m * 2 + nt];
          acc1 = __builtin_amdgcn_mfma_f32_16x16x32_f16(af[m], b1f[nt], acc1, 0, 0, 0);
          #pragma unroll
          for (int rr = 0; rr < 4; ++rr) {
            float h = acc1[rr] + bs;
            H1[(pp * 2 + m) * 4096 + HIDX(q * 4 + rr, col)] = (_Float16)(h > 0.f ? h : 0.f);
          }
        }
      }
    }
    __syncthreads();

    // GEMM2-chunk: M=96 (3 perms x 2 row-tiles x 16), K=256
    fx4 acc[12];
    #pragma unroll
    for (int i = 0; i < 12; ++i) acc[i] = zero4;
    #pragma unroll 2
    for (int kt = 0; kt < 8; ++kt) {
      half8 a[6];
      #pragma unroll
      for (int t = 0; t < 6; ++t)
        a[t] = *(const half8*)&H1[t * 4096 + ((kt * 4 + q) * 16 + l16) * 8];
      #pragma unroll
      for (int nt = 0; nt < 2; ++nt) {
        half8 b = *(const half8*)&pw2[(kt * 256 + colbase + nt * 16 + l16) * 32 + q * 8];
        #pragma unroll
        for (int t = 0; t < 6; ++t)
          acc[t * 2 + nt] = __builtin_amdgcn_mfma_f32_16x16x32_f16(a[t], b, acc[t * 2 + nt], 0, 0, 0);
      }
    }
    // relu + accumulate into agg (row-tile m = t&1)
    #pragma unroll
    for (int nt = 0; nt < 2; ++nt) {
      float bs = b2[colbase + nt * 16 + l16];
      #pragma unroll
      for (int t = 0; t < 6; ++t)
        #pragma unroll
        for (int rr = 0; rr < 4; ++rr) {
          float h = acc[t * 2 + nt][rr] + bs;
          if (h > 0.f) agg[(t & 1) * 2 + nt][rr] += h;
        }
    }
    __syncthreads();  // H1 reads done before next chunk's GEMM1 writes
  }

  // stage agg -> H1 tiles 0,1
  #pragma unroll
  for (int m = 0; m < 2; ++m)
    #pragma unroll
    for (int nt = 0; nt < 2; ++nt) {
      int col = colbase + nt * 16 + l16;
      #pragma unroll
      for (int rr = 0; rr < 4; ++rr)
        H1[m * 4096 + HIDX(q * 4 + rr, col)] = (_Float16)agg[m * 2 + nt][rr];
    }
  __syncthreads();

  // ---- GEMM3: r = relu(agg @ rho + br), M=32, K=256; r -> H1 tiles 2,3 ----
  fx4 acc3[4];
  #pragma unroll
  for (int i = 0; i < 4; ++i) acc3[i] = zero4;
  #pragma unroll 2
  for (int kt = 0; kt < 8; ++kt) {
    half8 a[2];
    #pragma unroll
    for (int m = 0; m < 2; ++m)
      a[m] = *(const half8*)&H1[m * 4096 + ((kt * 4 + q) * 16 + l16) * 8];
    #pragma unroll
    for (int nt = 0; nt < 2; ++nt) {
      half8 b = *(const half8*)&pwr[(kt * 256 + colbase + nt * 16 + l16) * 32 + q * 8];
      #pragma unroll
      for (int m = 0; m < 2; ++m)
        acc3[m * 2 + nt] = __builtin_amdgcn_mfma_f32_16x16x32_f16(a[m], b, acc3[m * 2 + nt], 0, 0, 0);
    }
  }
  #pragma unroll
  for (int m = 0; m < 2; ++m)
    #pragma unroll
    for (int nt = 0; nt < 2; ++nt) {
      int col = colbase + nt * 16 + l16;
      float bs = br[col];
      #pragma unroll
      for (int rr = 0; rr < 4; ++rr) {
        float h = acc3[m * 2 + nt][rr] + bs;
        H1[(2 + m) * 4096 + HIDX(q * 4 + rr, col)] = (_Float16)(h > 0.f ? h : 0.f);
      }
    }
  __syncthreads();

  // ---- heads: waves 0,1 compute [mean | log_std] = r @ PWh for row-tile = wave ----
  if (wave < 2) {
    fx4 a4 = zero4;
    for (int kt = 0; kt < 8; ++kt) {
      half8 a = *(const half8*)&H1[(2 + wave) * 4096 + ((kt * 4 + q) * 16 + l16) * 8];
      half8 b = *(const half8*)&pwh[(kt * 16 + l16) * 32 + q * 8];
      a4 = __builtin_amdgcn_mfma_f32_16x16x32_f16(a, b, a4, 0, 0, 0);
    }
    int gr = rowbase + wave * 16 + q * 4;
    if (l16 < 4) {
      float bias = bm[l16];
      #pragma unroll
      for (int rr = 0; rr < 4; ++rr) out[(gr + rr) * 4 + l16] = a4[rr] + bias;
    } else if (l16 < 8) {
      int c = l16 - 4;
      float bias = bl[c];
      #pragma unroll
      for (int rr = 0; rr < 4; ++rr) {
        float v = a4[rr] + bias;
        v = v < -20.f ? -20.f : (v > 2.f ? 2.f : v);
        out[BATCH * 4 + (gr + rr) * 4 + c] = v;
      }
    }
  }
}

extern "C" void kernel_launch(void* const* d_in, const int* in_sizes, int n_in,
                              void* d_out, int out_size, void* d_ws, size_t ws_size,
                              hipStream_t stream) {
  const float* obs  = (const float*)d_in[0];
  const float* lemb = (const float*)d_in[1];
  const float* w1   = (const float*)d_in[2];
  const float* b1   = (const float*)d_in[3];
  const float* w2   = (const float*)d_in[4];
  const float* b2   = (const float*)d_in[5];
  const float* wr   = (const float*)d_in[6];
  const float* br   = (const float*)d_in[7];
  const float* wm   = (const float*)d_in[8];
  const float* bm   = (const float*)d_in[9];
  const float* wl   = (const float*)d_in[10];
  const float* bl   = (const float*)d_in[11];
  float* out = (float*)d_out;
  _Float16* ws = (_Float16*)d_ws;

  hipLaunchKernelGGL(prep_weights, dim3(WS_TOTAL / 256), dim3(256), 0, stream,
                     w1, w2, wr, wm, wl, ws);
  hipLaunchKernelGGL(actor_fused, dim3(BATCH / TB), dim3(512), 0, stream,
                     obs, lemb, w1, (const _Float16*)ws, b1, b2, br, bm, bl, out);
}

// Round 12
// 199.884 us; speedup vs baseline: 1.1966x; 1.1448x over previous
//
#include <hip/hip_runtime.h>

#define BATCH 65536
#define TB 16

typedef _Float16 half8 __attribute__((ext_vector_type(8)));
typedef _Float16 half2v __attribute__((ext_vector_type(2)));
typedef float fx4 __attribute__((ext_vector_type(4)));

// workspace layout (halves)
#define PW1B_OFF 0        // [4][256][32]  W1 base rows (k<110, pad->128)
#define PW1F_OFF 32768    // [256][32]     W1 feat rows, k-map [feat_i(15) 0 feat_j(15) 0]
#define PW2_OFF  40960    // [8][256][32]
#define PWR_OFF  106496   // [8][256][32]
#define PWH_OFF  172032   // [8][16][32]   [mean_w | lstd_w | pad]
#define WS_TOTAL 176128

// A-layout index for a 16-row x 256-col tile, fragment-major:
// a-frag read for (kt,q,l16) at ((kt*4+q)*16+l16)*8 -> lane-contiguous b128.
// Adjacent even/odd cols are adjacent halves -> packed b32 staging writes.
#define HIDX(row, col) (((((col) >> 5) * 4 + (((col) >> 3) & 3)) * 16 + (row)) * 8 + ((col) & 7))

__global__ __launch_bounds__(256) void prep_weights(
    const float* __restrict__ w1, const float* __restrict__ w2,
    const float* __restrict__ wr, const float* __restrict__ wm,
    const float* __restrict__ wl, _Float16* __restrict__ ws)
{
  int idx = blockIdx.x * 256 + threadIdx.x;
  if (idx < 32768) {            // pw1b
    int kk = idx & 31, n = (idx >> 5) & 255, kt = idx >> 13;
    int k = kt * 32 + kk;
    ws[idx] = (k < 110) ? (_Float16)w1[k * 256 + n] : (_Float16)0.f;
  } else if (idx < 40960) {     // pw1f: kk 0-14 feat_i rows 113+, kk 16-30 feat_j rows 131+
    int t = idx - 32768;
    int kk = t & 31, n = t >> 5;
    _Float16 v = (_Float16)0.f;
    if (kk < 15)                  v = (_Float16)w1[(113 + kk) * 256 + n];
    else if (kk >= 16 && kk < 31) v = (_Float16)w1[(131 + (kk - 16)) * 256 + n];
    ws[idx] = v;
  } else if (idx < 106496) {    // pw2
    int t = idx - 40960;
    int kk = t & 31, n = (t >> 5) & 255, kt = t >> 13;
    ws[idx] = (_Float16)w2[(kt * 32 + kk) * 256 + n];
  } else if (idx < 172032) {    // pwr
    int t = idx - 106496;
    int kk = t & 31, n = (t >> 5) & 255, kt = t >> 13;
    ws[idx] = (_Float16)wr[(kt * 32 + kk) * 256 + n];
  } else if (idx < WS_TOTAL) {  // pwh
    int t = idx - 172032;
    int kk = t & 31, n = (t >> 5) & 15, kt = t >> 9;
    int k = kt * 32 + kk;
    _Float16 v = (_Float16)0.f;
    if (n < 4) v = (_Float16)wm[k * 4 + n];
    else if (n < 8) v = (_Float16)wl[k * 4 + (n - 4)];
    ws[PWH_OFF + t] = v;
  }
}

// R10/R11 post-mortem: R9 (TB=16, 512thr, full 6-perm phases, tiny reg set)
// is the optimum of this family; occupancy pins ~16 waves/CU regardless of
// LDS, so the levers left are barrier count and per-wave instruction count.
// R12 = R9 with: (a) barriers 6->4 (base+agg live in Bb: U needs no trailing
// barrier, agg-stage needs no preceding one); (b) bias-folded acc init for
// G2/G3 (-56 v_add/wave); (c) float2+packed-b32 staging (half the staging
// VMEM/LDS instrs). Math identical to R8-R11 (verified absmax 0.031).
__global__ __launch_bounds__(512) void actor_fused(
    const float* __restrict__ obs, const float* __restrict__ lemb,
    const float* __restrict__ w1, const _Float16* __restrict__ ws,
    const float* __restrict__ b1, const float* __restrict__ b2,
    const float* __restrict__ br, const float* __restrict__ bm,
    const float* __restrict__ bl, float* __restrict__ out)
{
  __shared__ __align__(16) _Float16 H1[6 * 16 * 256]; // 48 KB: h1_all; tile0 later holds r
  __shared__ __align__(16) _Float16 Bb[16 * 256];     //  8 KB: base (K=128), later agg (K=256)
  __shared__ __align__(16) _Float16 Os[3 * 16 * 16];  // 1.5 KB: compact obj tiles
  __shared__ __align__(16) _Float16 Bs[6 * 256];      //  3 KB: fused per-perm biases

  const _Float16* __restrict__ pw1b = ws + PW1B_OFF;
  const _Float16* __restrict__ pw1f = ws + PW1F_OFF;
  const _Float16* __restrict__ pw2  = ws + PW2_OFF;
  const _Float16* __restrict__ pwr  = ws + PWR_OFF;
  const _Float16* __restrict__ pwh  = ws + PWH_OFF;

  const int tid  = threadIdx.x;
  const int wave = tid >> 6;        // 0..7
  const int lane = tid & 63;
  const int q    = lane >> 4;
  const int l16  = lane & 15;
  const int colbase = wave * 32;    // this wave's 32 output cols
  const int rowbase = blockIdx.x * TB;

  // ---- stage base (16 rows x K=128) into Bb as 64 col-pairs/row ----
  for (int idx = tid; idx < 1024; idx += 512) {
    int r = idx >> 6, c2 = idx & 63, c = c2 * 2;
    float v0 = 0.f, v1 = 0.f;
    if (c2 < 50) {
      float2 v = ((const float2*)(lemb + (rowbase + r) * 100))[c2];
      v0 = v.x; v1 = v.y;
    } else if (c < 110) {
      v0 = obs[(rowbase + r) * 55 + (c - 100)];
      v1 = (c + 1 < 110) ? obs[(rowbase + r) * 55 + (c - 99)] : 0.f;
    }
    half2v hv = {(_Float16)v0, (_Float16)v1};
    *(half2v*)&Bb[HIDX(r, c)] = hv;  // even col -> adjacent halves, 4B aligned
  }
  // ---- compact obj tiles: 3 objects x 16 rows x 16 k (15 feats + pad) ----
  for (int idx = tid; idx < 768; idx += 512) {
    int o = idx >> 8, rem = idx & 255, r = rem >> 4, c = rem & 15;
    float v = (c < 15) ? obs[(rowbase + r) * 55 + 10 + o * 15 + c] : 0.f;
    Os[o * 256 + ((c >> 3) * 16 + r) * 8 + (c & 7)] = (_Float16)v;
  }
  // ---- fused per-perm biases: b1 + W1[onehot_i row] + W1[onehot_j row] ----
  for (int idx = tid; idx < 1536; idx += 512) {
    int p = idx >> 8, c = idx & 255;
    int oi = p >> 1, oj = (1161 >> (2 * p)) & 3;
    Bs[idx] = (_Float16)(b1[c] + w1[(110 + oi) * 256 + c] + w1[(128 + oj) * 256 + c]);
  }
  __syncthreads();  // B1

  const fx4 zero4 = {0.f, 0.f, 0.f, 0.f};

  // ---- U = base @ W1base (K=128), M=16, this wave's 32 cols ----
  fx4 u[2];
  u[0] = zero4; u[1] = zero4;
  #pragma unroll 2
  for (int kt = 0; kt < 4; ++kt) {
    half8 a = *(const half8*)&Bb[((kt * 4 + q) * 16 + l16) * 8];
    #pragma unroll
    for (int nt = 0; nt < 2; ++nt) {
      half8 b = *(const half8*)&pw1b[(kt * 256 + colbase + nt * 16 + l16) * 32 + q * 8];
      u[nt] = __builtin_amdgcn_mfma_f32_16x16x32_f16(a, b, u[nt], 0, 0, 0);
    }
  }
  // no barrier: Bb not written again until post-B2; H1 unread so far

  // preload perm-invariant GEMM1 feature-weight fragments
  half8 b1f[2];
  #pragma unroll
  for (int nt = 0; nt < 2; ++nt)
    b1f[nt] = *(const half8*)&pw1f[(colbase + nt * 16 + l16) * 32 + q * 8];

  // ---- GEMM1-all: h1_p = relu(U + F_p @ W1f + bias_p), p=0..5, K=32 ----
  // A k-map: quad 0,1 -> feat_i (k 0..15), quad 2,3 -> feat_j (k 16..31)
  #pragma unroll
  for (int p = 0; p < 6; ++p) {
    const int oi = p >> 1;
    const int oj = (1161 >> (2 * p)) & 3;
    const int o = (q < 2) ? oi : oj;
    half8 af = *(const half8*)&Os[o * 256 + ((q & 1) * 16 + l16) * 8];
    #pragma unroll
    for (int nt = 0; nt < 2; ++nt) {
      int col = colbase + nt * 16 + l16;
      fx4 acc1 = __builtin_amdgcn_mfma_f32_16x16x32_f16(af, b1f[nt], u[nt], 0, 0, 0);
      float bs = (float)Bs[p * 256 + col];
      #pragma unroll
      for (int rr = 0; rr < 4; ++rr) {
        float h = acc1[rr] + bs;
        H1[p * 4096 + HIDX(q * 4 + rr, col)] = (_Float16)(h > 0.f ? h : 0.f);
      }
    }
  }
  __syncthreads();  // B2: h1 ready

  // ---- GEMM2-all: M=96 (6 perms x 16 rows), K=256, bias-folded acc init ----
  float bsg[2];
  bsg[0] = b2[colbase + l16];
  bsg[1] = b2[colbase + 16 + l16];
  fx4 acc[12];
  #pragma unroll
  for (int i = 0; i < 12; ++i) {
    float bs = bsg[i & 1];
    acc[i][0] = bs; acc[i][1] = bs; acc[i][2] = bs; acc[i][3] = bs;
  }
  #pragma unroll 2
  for (int kt = 0; kt < 8; ++kt) {
    half8 a[6];
    #pragma unroll
    for (int p = 0; p < 6; ++p)
      a[p] = *(const half8*)&H1[p * 4096 + ((kt * 4 + q) * 16 + l16) * 8];
    #pragma unroll
    for (int nt = 0; nt < 2; ++nt) {
      half8 b = *(const half8*)&pw2[(kt * 256 + colbase + nt * 16 + l16) * 32 + q * 8];
      #pragma unroll
      for (int p = 0; p < 6; ++p)
        acc[p * 2 + nt] = __builtin_amdgcn_mfma_f32_16x16x32_f16(a[p], b, acc[p * 2 + nt], 0, 0, 0);
    }
  }
  // relu + sum the 6 row-groups -> agg; stage agg into Bb (dead since U; all
  // waves are past U because they are past B2) -- no barrier needed here.
  #pragma unroll
  for (int nt = 0; nt < 2; ++nt) {
    fx4 agg = zero4;
    #pragma unroll
    for (int p = 0; p < 6; ++p)
      #pragma unroll
      for (int rr = 0; rr < 4; ++rr) {
        float h = acc[p * 2 + nt][rr];
        if (h > 0.f) agg[rr] += h;
      }
    int col = colbase + nt * 16 + l16;
    #pragma unroll
    for (int rr = 0; rr < 4; ++rr)
      Bb[HIDX(q * 4 + rr, col)] = (_Float16)agg[rr];
  }
  __syncthreads();  // B3: agg complete in Bb; all H1 reads done

  // ---- GEMM3: r = relu(agg @ rho + br), M=16, K=256; r -> H1 tile 0 ----
  float bsr0 = br[colbase + l16];
  float bsr1 = br[colbase + 16 + l16];
  fx4 acc3[2];
  acc3[0][0] = bsr0; acc3[0][1] = bsr0; acc3[0][2] = bsr0; acc3[0][3] = bsr0;
  acc3[1][0] = bsr1; acc3[1][1] = bsr1; acc3[1][2] = bsr1; acc3[1][3] = bsr1;
  #pragma unroll 2
  for (int kt = 0; kt < 8; ++kt) {
    half8 a = *(const half8*)&Bb[((kt * 4 + q) * 16 + l16) * 8];
    #pragma unroll
    for (int nt = 0; nt < 2; ++nt) {
      half8 b = *(const half8*)&pwr[(kt * 256 + colbase + nt * 16 + l16) * 32 + q * 8];
      acc3[nt] = __builtin_amdgcn_mfma_f32_16x16x32_f16(a, b, acc3[nt], 0, 0, 0);
    }
  }
  #pragma unroll
  for (int nt = 0; nt < 2; ++nt) {
    int col = colbase + nt * 16 + l16;
    #pragma unroll
    for (int rr = 0; rr < 4; ++rr) {
      float h = acc3[nt][rr];
      H1[HIDX(q * 4 + rr, col)] = (_Float16)(h > 0.f ? h : 0.f);
    }
  }
  __syncthreads();  // B4: r ready

  // ---- heads: wave 0 computes [mean | log_std] = r @ PWh (N padded 16) ----
  if (wave == 0) {
    fx4 a4 = zero4;
    for (int kt = 0; kt < 8; ++kt) {
      half8 a = *(const half8*)&H1[((kt * 4 + q) * 16 + l16) * 8];
      half8 b = *(const half8*)&pwh[(kt * 16 + l16) * 32 + q * 8];
      a4 = __builtin_amdgcn_mfma_f32_16x16x32_f16(a, b, a4, 0, 0, 0);
    }
    int gr = rowbase + q * 4;
    if (l16 < 4) {
      float bias = bm[l16];
      #pragma unroll
      for (int rr = 0; rr < 4; ++rr) out[(gr + rr) * 4 + l16] = a4[rr] + bias;
    } else if (l16 < 8) {
      int c = l16 - 4;
      float bias = bl[c];
      #pragma unroll
      for (int rr = 0; rr < 4; ++rr) {
        float v = a4[rr] + bias;
        v = v < -20.f ? -20.f : (v > 2.f ? 2.f : v);
        out[BATCH * 4 + (gr + rr) * 4 + c] = v;
      }
    }
  }
}

extern "C" void kernel_launch(void* const* d_in, const int* in_sizes, int n_in,
                              void* d_out, int out_size, void* d_ws, size_t ws_size,
                              hipStream_t stream) {
  const float* obs  = (const float*)d_in[0];
  const float* lemb = (const float*)d_in[1];
  const float* w1   = (const float*)d_in[2];
  const float* b1   = (const float*)d_in[3];
  const float* w2   = (const float*)d_in[4];
  const float* b2   = (const float*)d_in[5];
  const float* wr   = (const float*)d_in[6];
  const float* br   = (const float*)d_in[7];
  const float* wm   = (const float*)d_in[8];
  const float* bm   = (const float*)d_in[9];
  const float* wl   = (const float*)d_in[10];
  const float* bl   = (const float*)d_in[11];
  float* out = (float*)d_out;
  _Float16* ws = (_Float16*)d_ws;

  hipLaunchKernelGGL(prep_weights, dim3(WS_TOTAL / 256), dim3(256), 0, stream,
                     w1, w2, wr, wm, wl, ws);
  hipLaunchKernelGGL(actor_fused, dim3(BATCH / TB), dim3(512), 0, stream,
                     obs, lemb, w1, (const _Float16*)ws, b1, b2, br, bm, bl, out);
}